// Round 2
// 247.814 us; speedup vs baseline: 1.0369x; 1.0369x over previous
//
#include <hip/hip_runtime.h>

// out[b,j,hw] = exp( sum_i log(relu(x[b,i,hw])+0.1) * E[i,j] ) + bias[j]
// x: (B=32, NC=64, H=128, W=128) fp32.
#define NCH 64
#define HWSZ 16384            // 128*128
#define NPOINTS (32 * HWSZ)   // 524288
#define TILE_P 64             // spatial points per block
#define JPT 16                // j-channels per thread in phase 2 (4 waves * 16 = 64)

// R4/R5: split j across the 4 waves of a block (16 acc/thread, not 64) and
// share log(x) for a 64-point tile via LDS. Removes the R0 pathology where
// acc[64] at VGPR_Count=40 forced shadow-register traffic around every fmac
// (VALU busy 47us vs 27.3us bare-fmac floor).
//
// R5 hardening vs R4 (which passed pre-timing at absmax 0.0156 but tripped the
// post-timing divergence check): __launch_bounds__ relaxed 8 -> 4 blocks/CU.
// The (256,8) bound hard-capped VGPRs at 64; phase 1 keeps ~16 loads in
// flight + acc[16] + addressing, so spill-to-scratch was plausible, and
// scratch is the one kernel-side mechanism tied to graph-replay-dependent
// behavior. (256,4) gives <=128 VGPRs: zero spill risk, 16 waves/CU -- still
// above the 43% occupancy measured in R0. All indexing re-audited: phase-1
// writes cover lxs[0..63][0..63] exactly once; one __syncthreads orders
// write->read; per-thread (j,p) output pairs disjoint; no OOB anywhere.
// Success signals: VGPR 48-64 (no scratch), LDS=16384, dur_us ~50-58,
// inner loop = 1 ds_read_b32 + 16 v_fmac_f32 (SGPR E operand).
__global__ __launch_bounds__(256, 4) void fused_log_einsum_exp(
    const float* __restrict__ x,
    const float* __restrict__ E,     // (64,64) row-major: E[i*64+j]
    const float* __restrict__ bias,  // (64)
    float* __restrict__ out)
{
    __shared__ float lxs[NCH][TILE_P];   // 16 KB

    const int t   = threadIdx.x;
    const int p0  = blockIdx.x * TILE_P;   // first point of this tile
    const int b   = p0 >> 14;              // p0 / HWSZ (tile never crosses b)
    const int hw0 = p0 & (HWSZ - 1);

    const float* xb = x   + (size_t)b * NCH * HWSZ + hw0;
    float*       ob = out + (size_t)b * NCH * HWSZ + hw0;

    // ---- Phase 1: load 64ch x 64pt tile, log once, stage in LDS ----
    // wave w handles channels [w*16, w*16+16); lane = point -> every global
    // load is a contiguous 256B/wave segment; every LDS write is a
    // contiguous 256B row (conflict-free).
    {
        const int p  = t & 63;
        const int i0 = (t >> 6) * 16;
        #pragma unroll
        for (int k = 0; k < 16; ++k) {
            const int i = i0 + k;
            float v = xb[(size_t)i * HWSZ + p];
            lxs[i][p] = __logf(fmaxf(v, 0.0f) + 0.1f);
        }
    }
    __syncthreads();

    // ---- Phase 2: thread = (point, 16-wide j-slice). j0 is wave-uniform;
    // readfirstlane makes that provable so E/bias stay s_load (SGPR operand
    // feeds v_fmac directly -- one SGPR read per VALU instr is legal).
    const int p  = t & 63;
    const int j0 = __builtin_amdgcn_readfirstlane((t >> 6) * JPT);

    float acc[JPT];
    #pragma unroll
    for (int k = 0; k < JPT; ++k) acc[k] = 0.0f;

    #pragma unroll 4
    for (int i = 0; i < NCH; ++i) {
        const float lx = lxs[i][p];          // contiguous across lanes: no conflict
        #pragma unroll
        for (int k = 0; k < JPT; ++k)
            acc[k] = fmaf(lx, E[i * NCH + j0 + k], acc[k]);
    }

    // ---- Epilogue: exp + bias, coalesced 256B/wave stores per j ----
    #pragma unroll
    for (int k = 0; k < JPT; ++k)
        ob[(size_t)(j0 + k) * HWSZ + p] = __expf(acc[k]) + bias[j0 + k];
}

extern "C" void kernel_launch(void* const* d_in, const int* in_sizes, int n_in,
                              void* d_out, int out_size, void* d_ws, size_t ws_size,
                              hipStream_t stream) {
    const float* x    = (const float*)d_in[0];
    const float* E    = (const float*)d_in[1];   // (64,64,1,1) -> [i*64+j]
    const float* bias = (const float*)d_in[2];   // (64,1,1)
    float* out = (float*)d_out;

    dim3 grid(NPOINTS / TILE_P), block(256);
    hipLaunchKernelGGL(fused_log_einsum_exp, grid, block, 0, stream,
                       x, E, bias, out);
}

// Round 4
// 244.356 us; speedup vs baseline: 1.0515x; 1.0142x over previous
//
#include <hip/hip_runtime.h>

// out[b,j,hw] = exp( sum_i log(relu(x[b,i,hw])+0.1) * E[i,j] ) + bias[j]
// x: (B=32, NC=64, H=128, W=128) fp32.
//
// R6 (resubmit -- R3 slot hit GPUAcquisitionTimeout, kernel never ran).
// R0 and R2 both stalled at ~102us / ~50% VALUBusy with ~2TB/s: the inner
// loop consumed E via s_load mixed with lgkmcnt-counted data reads ->
// per-chunk lgkmcnt(0) drains (SMEM is out-of-order in lgkmcnt) serialized
// every unrolled chunk. Fix: compute the TRANSPOSED gemm
//   out^T[j][p] = sum_i E^T[j][i] * lx[i][p]
// with v_mfma_f32_16x16x32_bf16 (split bf16 hi/lo, fp32 accum):
//  - A-frags (E^T) loaded ONCE per block into VGPRs: zero E traffic in loop.
//  - In C^T form each wave owns 16 points x all 64 j, so its lx slab is
//    wave-private: global->VGPR direct, log + split in-register.
//    NO LDS, NO barriers, NO s_load in the loop, no shared-operand waits.
// Fragment layouts (AMD standard for 16x16x32, K-run contiguous per lane):
//   A: lane l holds A[row=l&15][k=(l>>4)*8+e]
//   B: lane l holds B[k=(l>>4)*8+e][col=l&15]
//   D: lane l, reg r holds D[row=(l>>4)*4+r][col=l&15]   (guide m89-verified)
// With harness E=identity, D=B exercises B<->D consistency; an A-transpose
// error would be invisible for identity E (G9 caveat) but E is stated
// row-major E[i*64+j] and A=E^T per the math above.
// Accuracy: hi=trunc(lx), lo=trunc(lx-hi); acc += hh*Eh + hh*El + lh*Eh;
// dropped lo*lo term <= 2^-16*|arg| -> ~+0.003 absmax on top of 0.0156.
// Success signals: dur ~45-60us, VALUBusy ~20%, LDS=0, MfmaUtil ~3%.
#define NCH 64
#define HWSZ 16384
#define NPOINTS (32 * HWSZ)      // 524288
#define NTILES (NPOINTS / 64)    // 8192 block-tiles: 4 waves x 16 pts
#define NBLOCKS 1024             // 8 tiles per block, exact

typedef __attribute__((ext_vector_type(8))) short bf16x8;  // 8 bf16 in 4 VGPRs
typedef __attribute__((ext_vector_type(4))) float f32x4;

static __device__ __forceinline__ unsigned short bf16_trunc(float f) {
    return (unsigned short)(__float_as_uint(f) >> 16);
}
static __device__ __forceinline__ float bf16_up(unsigned short h) {
    return __uint_as_float((unsigned)h << 16);
}

__global__ __launch_bounds__(256, 2) void fused_log_einsum_exp(
    const float* __restrict__ x,
    const float* __restrict__ E,     // (64,64) row-major: E[i*64+j]
    const float* __restrict__ bias,  // (64)
    float* __restrict__ out)
{
    const int lane = threadIdx.x & 63;
    const int wv   = threadIdx.x >> 6;   // wave 0..3 within block
    const int lg   = lane >> 4;          // k-group 0..3
    const int ln   = lane & 15;          // row/col-in-fragment 0..15

    // ---- A-frags: E^T (row=j, k=i), hi/lo split. Loaded once per block.
    // a[m][kk]: m = j-tile (4 x 16 j), kk = k-step (2 x 32 i).
    bf16x8 ah[4][2], al[4][2];
    #pragma unroll
    for (int m = 0; m < 4; ++m) {
        #pragma unroll
        for (int kk = 0; kk < 2; ++kk) {
            bf16x8 h, l;
            #pragma unroll
            for (int e = 0; e < 8; ++e) {
                const int i = kk * 32 + lg * 8 + e;
                const int j = m * 16 + ln;
                const float v = E[i * NCH + j];
                const unsigned short hh = bf16_trunc(v);
                h[e] = (short)hh;
                l[e] = (short)bf16_trunc(v - bf16_up(hh));
            }
            ah[m][kk] = h; al[m][kk] = l;
        }
    }

    // bias for the 16 j's this lane will store: j = m*16 + lg*4 + r
    float bv[4][4];
    #pragma unroll
    for (int m = 0; m < 4; ++m)
        #pragma unroll
        for (int r = 0; r < 4; ++r)
            bv[m][r] = bias[m * 16 + lg * 4 + r];

    // ---- Grid-stride over 16-point wave-tiles (wave-private lx slabs).
    for (int t = blockIdx.x; t < NTILES; t += NBLOCKS) {
        const int p0 = t * 64 + wv * 16;                    // never crosses b
        const size_t base = (size_t)(p0 & ~(HWSZ - 1)) * NCH // b*64*HWSZ
                          + (size_t)(p0 & (HWSZ - 1)) + ln;  // + hw + point

        // 16 gather loads: channel i = kk*32 + lg*8 + e at point p0+ln.
        // Per instr: 4 x 64B segments; sibling waves fill adjacent segments.
        float xr[2][8];
        #pragma unroll
        for (int kk = 0; kk < 2; ++kk)
            #pragma unroll
            for (int e = 0; e < 8; ++e)
                xr[kk][e] = x[base + (size_t)(kk * 32 + lg * 8 + e) * HWSZ];

        // log + hi/lo bf16 split, in-register (B-frags, wave-private).
        bf16x8 bh[2], bl[2];
        #pragma unroll
        for (int kk = 0; kk < 2; ++kk) {
            bf16x8 h, l;
            #pragma unroll
            for (int e = 0; e < 8; ++e) {
                const float lx = __logf(fmaxf(xr[kk][e], 0.0f) + 0.1f);
                const unsigned short hh = bf16_trunc(lx);
                h[e] = (short)hh;
                l[e] = (short)bf16_trunc(lx - bf16_up(hh));
            }
            bh[kk] = h; bl[kk] = l;
        }

        // 24 MFMAs: 4 j-tiles x 2 k-steps x (hh + hl + lh).
        #pragma unroll
        for (int m = 0; m < 4; ++m) {
            f32x4 acc = {0.f, 0.f, 0.f, 0.f};
            #pragma unroll
            for (int kk = 0; kk < 2; ++kk) {
                acc = __builtin_amdgcn_mfma_f32_16x16x32_bf16(ah[m][kk], bh[kk], acc, 0, 0, 0);
                acc = __builtin_amdgcn_mfma_f32_16x16x32_bf16(ah[m][kk], bl[kk], acc, 0, 0, 0);
                acc = __builtin_amdgcn_mfma_f32_16x16x32_bf16(al[m][kk], bh[kk], acc, 0, 0, 0);
            }
            // Epilogue: exp + bias; store D[row=j][col=point].
            #pragma unroll
            for (int r = 0; r < 4; ++r) {
                const int j = m * 16 + lg * 4 + r;
                out[base + (size_t)j * HWSZ] = __expf(acc[r]) + bv[m][r];
            }
        }
    }
}

extern "C" void kernel_launch(void* const* d_in, const int* in_sizes, int n_in,
                              void* d_out, int out_size, void* d_ws, size_t ws_size,
                              hipStream_t stream) {
    const float* x    = (const float*)d_in[0];
    const float* E    = (const float*)d_in[1];   // (64,64,1,1) -> [i*64+j]
    const float* bias = (const float*)d_in[2];   // (64,1,1)
    float* out = (float*)d_out;

    dim3 grid(NBLOCKS), block(256);
    hipLaunchKernelGGL(fused_log_einsum_exp, grid, block, 0, stream,
                       x, E, bias, out);
}